// Round 2
// baseline (573.019 us; speedup 1.0000x reference)
//
#include <hip/hip_runtime.h>
#include <hip/hip_bf16.h>
#include <stdint.h>

// ---------------------------------------------------------------------------
// EquilibriumPropagationNet free-phase settle, fused, split-bf16 precision.
//   c1 = 0.5*x@W1 + b1   (fp32 in ws, via 3-term split-bf16 MFMA GEMM)
//   50x: u1 = 0.5*(u1 + d1*(c1 + W2·r2));  u2 = 0.5*(u2 + d2*(r1@W2 + b2))
//   out = sigmoid(u2)
// u1/u2/c1 state fp32; every MFMA operand is hi/lo-split bf16 (rel err ~2^-16).
// ---------------------------------------------------------------------------

typedef __attribute__((ext_vector_type(8))) short bf16x8;
typedef __attribute__((ext_vector_type(4))) float f32x4;

#define D_IN  784
#define KPAD  800
#define HID   1024
#define D_OUT 10

__device__ __forceinline__ uint32_t fbits(float f){ union{float f;uint32_t u;}v; v.f=f; return v.u; }
__device__ __forceinline__ float asf(uint32_t u){ union{uint32_t u;float f;}v; v.u=u; return v.f; }
__device__ __forceinline__ unsigned short f2bf(float f){ __hip_bfloat16 h=__float2bfloat16(f); return *reinterpret_cast<unsigned short*>(&h); }
__device__ __forceinline__ uint32_t pack2(unsigned short a, unsigned short b){ return (uint32_t)a | ((uint32_t)b<<16); }
__device__ __forceinline__ float sigmoidf_(float x){ return __builtin_amdgcn_rcpf(1.0f + __expf(-x)); }

// ---------------- prep: W1 (f32 [784][1024]) -> W1^T hi/lo bf16 [1024][800]
__global__ void prep_w1t(const float* __restrict__ W1,
                         unsigned short* __restrict__ w1h, unsigned short* __restrict__ w1l) {
    __shared__ float tile[32][33];
    int kt = blockIdx.x % 25;     // 25 k-tiles cover KPAD=800
    int nt = blockIdx.x / 25;     // 32 n-tiles
    int t  = threadIdx.x;
    int kk = t / 8;               // 0..31
    int nn = (t % 8) * 4;         // 0..28
    int k  = kt * 32 + kk;
    float4 v = make_float4(0.f, 0.f, 0.f, 0.f);
    if (k < D_IN)
        v = *reinterpret_cast<const float4*>(W1 + (size_t)k * HID + nt * 32 + nn);
    tile[kk][nn + 0] = v.x; tile[kk][nn + 1] = v.y;
    tile[kk][nn + 2] = v.z; tile[kk][nn + 3] = v.w;
    __syncthreads();
    int nn2 = t / 8;
    int kk2 = (t % 8) * 4;
    unsigned short hs[4], ls[4];
#pragma unroll
    for (int i = 0; i < 4; i++) {
        float f = tile[kk2 + i][nn2];
        uint32_t hb = fbits(f) & 0xffff0000u;
        hs[i] = (unsigned short)(hb >> 16);
        ls[i] = f2bf(f - asf(hb));
    }
    size_t o = (size_t)(nt * 32 + nn2) * KPAD + kt * 32 + kk2;
    uint2 hv; hv.x = pack2(hs[0], hs[1]); hv.y = pack2(hs[2], hs[3]);
    uint2 lv; lv.x = pack2(ls[0], ls[1]); lv.y = pack2(ls[2], ls[3]);
    *reinterpret_cast<uint2*>(w1h + o) = hv;
    *reinterpret_cast<uint2*>(w1l + o) = lv;
}

// ---------------- GEMM: c1 = fp32(0.5*x@W1 + b1)   [16384][1024] f32
// 128x128 tile, BK=32, 4 waves (2x2), 3-term split-bf16 MFMA, x split on the fly.
__global__ __launch_bounds__(256) void gemm_c1(
    const float* __restrict__ x,
    const unsigned short* __restrict__ w1h, const unsigned short* __restrict__ w1l,
    const float* __restrict__ b1, float* __restrict__ c1)
{
    __shared__ unsigned short Ah[128][40];   // +8 pad: kills 8-way bank conflict
    __shared__ unsigned short Al[128][40];
    __shared__ unsigned short Bh[128][40];
    __shared__ unsigned short Bl[128][40];
    int bm = blockIdx.x >> 3;       // 128 m-tiles
    int bn = blockIdx.x & 7;        // 8 n-tiles
    int t = threadIdx.x;
    int lane = t & 63;
    int wid  = t >> 6;
    int r = lane & 15, g = lane >> 4;
    int wm = wid >> 1, wn = wid & 1;

    f32x4 acc[4][4];
    f32x4 zero = {0.f, 0.f, 0.f, 0.f};
#pragma unroll
    for (int i = 0; i < 4; i++)
#pragma unroll
        for (int j = 0; j < 4; j++) acc[i][j] = zero;

    int srow  = t >> 1;
    int skoff = (t & 1) * 16;
    const float* xbase = x + (size_t)(bm * 128 + srow) * D_IN;
    const unsigned short* bhp = w1h + (size_t)(bn * 128 + srow) * KPAD + skoff;
    const unsigned short* blp = w1l + (size_t)(bn * 128 + srow) * KPAD + skoff;

    for (int kt = 0; kt < KPAD / 32; kt++) {
        int k0 = kt * 32 + skoff;
        float xv[16];
        if (k0 < D_IN) {
#pragma unroll
            for (int c = 0; c < 4; c++) {
                float4 f = *reinterpret_cast<const float4*>(xbase + k0 + 4 * c);
                xv[4*c+0]=f.x; xv[4*c+1]=f.y; xv[4*c+2]=f.z; xv[4*c+3]=f.w;
            }
        } else {
#pragma unroll
            for (int i = 0; i < 16; i++) xv[i] = 0.f;
        }
        uint4 vbh0 = *reinterpret_cast<const uint4*>(bhp + kt * 32);
        uint4 vbh1 = *reinterpret_cast<const uint4*>(bhp + kt * 32 + 8);
        uint4 vbl0 = *reinterpret_cast<const uint4*>(blp + kt * 32);
        uint4 vbl1 = *reinterpret_cast<const uint4*>(blp + kt * 32 + 8);
        uint32_t hw[8], lw[8];
#pragma unroll
        for (int j = 0; j < 8; j++) {
            float f0 = xv[2*j], f1 = xv[2*j+1];
            uint32_t hb0 = fbits(f0) & 0xffff0000u;
            uint32_t hb1 = fbits(f1) & 0xffff0000u;
            hw[j] = (hb0 >> 16) | hb1;
            lw[j] = pack2(f2bf(f0 - asf(hb0)), f2bf(f1 - asf(hb1)));
        }
        __syncthreads();
        *reinterpret_cast<uint4*>(&Ah[srow][skoff])     = make_uint4(hw[0],hw[1],hw[2],hw[3]);
        *reinterpret_cast<uint4*>(&Ah[srow][skoff + 8]) = make_uint4(hw[4],hw[5],hw[6],hw[7]);
        *reinterpret_cast<uint4*>(&Al[srow][skoff])     = make_uint4(lw[0],lw[1],lw[2],lw[3]);
        *reinterpret_cast<uint4*>(&Al[srow][skoff + 8]) = make_uint4(lw[4],lw[5],lw[6],lw[7]);
        *reinterpret_cast<uint4*>(&Bh[srow][skoff])     = vbh0;
        *reinterpret_cast<uint4*>(&Bh[srow][skoff + 8]) = vbh1;
        *reinterpret_cast<uint4*>(&Bl[srow][skoff])     = vbl0;
        *reinterpret_cast<uint4*>(&Bl[srow][skoff + 8]) = vbl1;
        __syncthreads();
        bf16x8 ah[4], al[4], bh[4], bl[4];
#pragma unroll
        for (int mt = 0; mt < 4; mt++) {
            ah[mt] = *reinterpret_cast<const bf16x8*>(&Ah[wm * 64 + mt * 16 + r][g * 8]);
            al[mt] = *reinterpret_cast<const bf16x8*>(&Al[wm * 64 + mt * 16 + r][g * 8]);
        }
#pragma unroll
        for (int nt = 0; nt < 4; nt++) {
            bh[nt] = *reinterpret_cast<const bf16x8*>(&Bh[wn * 64 + nt * 16 + r][g * 8]);
            bl[nt] = *reinterpret_cast<const bf16x8*>(&Bl[wn * 64 + nt * 16 + r][g * 8]);
        }
#pragma unroll
        for (int mt = 0; mt < 4; mt++)
#pragma unroll
            for (int nt = 0; nt < 4; nt++) {
                acc[mt][nt] = __builtin_amdgcn_mfma_f32_16x16x32_bf16(ah[mt], bh[nt], acc[mt][nt], 0, 0, 0);
                acc[mt][nt] = __builtin_amdgcn_mfma_f32_16x16x32_bf16(al[mt], bh[nt], acc[mt][nt], 0, 0, 0);
                acc[mt][nt] = __builtin_amdgcn_mfma_f32_16x16x32_bf16(ah[mt], bl[nt], acc[mt][nt], 0, 0, 0);
            }
    }
#pragma unroll
    for (int nt = 0; nt < 4; nt++) {
        int n = bn * 128 + wn * 64 + nt * 16 + r;
        float bias = b1[n];
#pragma unroll
        for (int mt = 0; mt < 4; mt++) {
            int mrow = bm * 128 + wm * 64 + mt * 16 + g * 4;
#pragma unroll
            for (int q = 0; q < 4; q++)
                c1[(size_t)(mrow + q) * HID + n] = 0.5f * acc[mt][nt][q] + bias;
        }
    }
}

// ---------------- fused settle: 1 block = 16 rows, 8 waves, wave w owns 128 h.
// u1,c1 fp32 in registers; r1 stashed hi/lo bf16 in LDS; all MFMA split-exact.
__global__ __launch_bounds__(512, 2) void settle(
    const float* __restrict__ u1g, const float* __restrict__ u2g,
    const float* __restrict__ W2,  const float* __restrict__ b2,
    const float* __restrict__ c1,  const int* __restrict__ steps_ptr,
    float* __restrict__ out)
{
    __shared__ unsigned short r1hi[8][16][128];   // 32 KB, per-wave slab, XOR swizzled
    __shared__ unsigned short r1lo[8][16][128];   // 32 KB
    __shared__ float s_part[8][16][16];           // 8 KB
    __shared__ float u2s[16][16];
    __shared__ unsigned short r2p[16][40];        // packed B: [hi|hi|lo|0] per row
    __shared__ float b2s[16];

    int t = threadIdx.x;
    int w = t >> 6, lane = t & 63;
    int r = lane & 15, g = lane >> 4;
    int row0 = blockIdx.x * 16;
    int h0 = w * 128;

    // zero pad slots 30..39 of r2p (slots 30,31 are read by the B-frag)
    if (t < 160) { int rr = t / 10, kk = 30 + t % 10; r2p[rr][kk] = 0; }
    // init u2 state + packed r2
    if (t < 160) {
        int rr = t / 10, k = t % 10;
        float uv = u2g[(size_t)(row0 + rr) * D_OUT + k];
        u2s[rr][k] = uv;
        float rv = sigmoidf_(uv);
        uint32_t hb = fbits(rv) & 0xffff0000u;
        unsigned short hi = (unsigned short)(hb >> 16);
        unsigned short lo = f2bf(rv - asf(hb));
        r2p[rr][k] = hi; r2p[rr][k + 10] = hi; r2p[rr][k + 20] = lo;
    }
    if (t < 16) b2s[t] = (t < D_OUT) ? b2[t] : 0.f;

    // per-lane fp32 state
    f32x4 u1f[8], c1f[8];
#pragma unroll
    for (int tt = 0; tt < 8; tt++) {
        int h = h0 + tt * 16 + 4 * g;
        u1f[tt] = *reinterpret_cast<const f32x4*>(u1g + (size_t)(row0 + r) * HID + h);
        c1f[tt] = *reinterpret_cast<const f32x4*>(c1  + (size_t)(row0 + r) * HID + h);
    }

    // phase-1 A frags: K-packed [W2hi(10) | W2lo(10) | W2hi(10) | 0,0]
    bf16x8 aW2[8];
#pragma unroll
    for (int tt = 0; tt < 8; tt++) {
        int h = h0 + tt * 16 + r;
#pragma unroll
        for (int j = 0; j < 8; j++) {
            int s = 8 * g + j;
            unsigned short val = 0;
            if (s < 30) {
                int k = (s < 10) ? s : (s < 20 ? s - 10 : s - 20);
                float f = W2[(size_t)h * D_OUT + k];
                uint32_t hb = fbits(f) & 0xffff0000u;
                val = (s >= 10 && s < 20) ? f2bf(f - asf(hb)) : (unsigned short)(hb >> 16);
            }
            aW2[tt][j] = (short)val;
        }
    }
    // phase-2 B frags: hi and lo
    bf16x8 bWh[4], bWl[4];
#pragma unroll
    for (int kt = 0; kt < 4; kt++)
#pragma unroll
        for (int j = 0; j < 8; j++) {
            unsigned short vh = 0, vl = 0;
            if (r < D_OUT) {
                int h = h0 + kt * 32 + 8 * g + j;
                float f = W2[(size_t)h * D_OUT + r];
                uint32_t hb = fbits(f) & 0xffff0000u;
                vh = (unsigned short)(hb >> 16);
                vl = f2bf(f - asf(hb));
            }
            bWh[kt][j] = (short)vh; bWl[kt][j] = (short)vl;
        }

    int steps = steps_ptr[0];
    __syncthreads();

    const uint32_t swz = (uint32_t)((r & 7) << 4);   // XOR on bits 4-6 of row-local byte off
    char* myhi = (char*)(&r1hi[w][r][0]);
    char* mylo = (char*)(&r1lo[w][r][0]);
    f32x4 zero = {0.f, 0.f, 0.f, 0.f};

    for (int s = 0; s < steps; s++) {
        // ---- phase 1: m1 = W2*r2 (split-exact in one MFMA); update u1; stash r1 hi/lo
        bf16x8 br2 = *reinterpret_cast<const bf16x8*>(&r2p[r][8 * g]);
#pragma unroll
        for (int tt = 0; tt < 8; tt++) {
            f32x4 m1 = __builtin_amdgcn_mfma_f32_16x16x32_bf16(aW2[tt], br2, zero, 0, 0, 0);
            f32x4 u = u1f[tt], un;
            uint32_t hb[4]; unsigned short lo[4];
#pragma unroll
            for (int q = 0; q < 4; q++) {
                float rv = sigmoidf_(u[q]);            // r1 from OLD u1 (full fp32)
                hb[q] = fbits(rv) & 0xffff0000u;
                lo[q] = f2bf(rv - asf(hb[q]));
                float d1 = __builtin_fmaf(-rv, rv, rv);
                float t1 = c1f[tt][q] + m1[q];
                un[q] = 0.5f * __builtin_fmaf(d1, t1, u[q]);
            }
            u1f[tt] = un;
            uint2 hv; hv.x = (hb[0] >> 16) | hb[1]; hv.y = (hb[2] >> 16) | hb[3];
            uint2 lv; lv.x = pack2(lo[0], lo[1]);   lv.y = pack2(lo[2], lo[3]);
            uint32_t off = (uint32_t)(tt * 32 + 8 * g);   // bytes: (tt*16+4g)*2
            *reinterpret_cast<uint2*>(myhi + (off ^ swz)) = hv;
            *reinterpret_cast<uint2*>(mylo + (off ^ swz)) = lv;
        }
        // ---- phase 2: s_part = r1 @ W2, 3-term split
        f32x4 sacc = zero;
#pragma unroll
        for (int kt = 0; kt < 4; kt++) {
            uint32_t off = (uint32_t)(kt * 64 + 16 * g);  // bytes: (kt*32+8g)*2
            bf16x8 ah = *reinterpret_cast<const bf16x8*>(myhi + (off ^ swz));
            bf16x8 al = *reinterpret_cast<const bf16x8*>(mylo + (off ^ swz));
            sacc = __builtin_amdgcn_mfma_f32_16x16x32_bf16(ah, bWh[kt], sacc, 0, 0, 0);
            sacc = __builtin_amdgcn_mfma_f32_16x16x32_bf16(al, bWh[kt], sacc, 0, 0, 0);
            sacc = __builtin_amdgcn_mfma_f32_16x16x32_bf16(ah, bWl[kt], sacc, 0, 0, 0);
        }
#pragma unroll
        for (int q = 0; q < 4; q++) s_part[w][4 * g + q][r] = sacc[q];
        __syncthreads();
        // ---- u2 update (160 threads)
        if (t < 16 * D_OUT) {
            int rr = t / D_OUT, k = t - rr * D_OUT;
            float sv = b2s[k];
#pragma unroll
            for (int ww = 0; ww < 8; ww++) sv += s_part[ww][rr][k];
            float uo = u2s[rr][k];
            float r2o = sigmoidf_(uo);
            float d2 = __builtin_fmaf(-r2o, r2o, r2o);
            float un2 = 0.5f * __builtin_fmaf(d2, sv, uo);
            u2s[rr][k] = un2;
            float rn = sigmoidf_(un2);
            uint32_t hb = fbits(rn) & 0xffff0000u;
            unsigned short hi = (unsigned short)(hb >> 16);
            r2p[rr][k] = hi; r2p[rr][k + 10] = hi; r2p[rr][k + 20] = f2bf(rn - asf(hb));
        }
        __syncthreads();
    }

    if (t < 16 * D_OUT) {
        int rr = t / D_OUT, k = t - rr * D_OUT;
        out[(size_t)(row0 + rr) * D_OUT + k] = sigmoidf_(u2s[rr][k]);
    }
}

// ---------------------------------------------------------------------------
extern "C" void kernel_launch(void* const* d_in, const int* in_sizes, int n_in,
                              void* d_out, int out_size, void* d_ws, size_t ws_size,
                              hipStream_t stream) {
    const float* x   = (const float*)d_in[0];
    const float* u1  = (const float*)d_in[1];
    const float* u2  = (const float*)d_in[2];
    const float* W1  = (const float*)d_in[3];
    const float* W2  = (const float*)d_in[4];
    const float* b1  = (const float*)d_in[5];
    const float* b2  = (const float*)d_in[6];
    const int* steps = (const int*)d_in[7];
    float* out = (float*)d_out;

    // ws layout (~67.1 MB):
    //   [0)         c1  f32  [16384][1024]  67,108,864 B
    //   [67108864)  w1h bf16 [1024][800]     1,638,400 B
    //   [68747264)  w1l bf16 [1024][800]     1,638,400 B
    char* ws = (char*)d_ws;
    float* c1           = (float*)(ws);
    unsigned short* w1h = (unsigned short*)(ws + 67108864u);
    unsigned short* w1l = (unsigned short*)(ws + 67108864u + 1638400u);

    prep_w1t<<<800,  256, 0, stream>>>(W1, w1h, w1l);
    gemm_c1 <<<1024, 256, 0, stream>>>(x, w1h, w1l, b1, c1);
    settle  <<<1024, 512, 0, stream>>>(u1, u2, W2, b2, c1, steps, out);
}